// Round 3
// baseline (401.975 us; speedup 1.0000x reference)
//
#include <hip/hip_runtime.h>

__device__ __forceinline__ float2 cmulf(float2 a, float c, float s) {
    return make_float2(a.x * c - a.y * s, a.x * s + a.y * c);
}

// LDS anti-bank-conflict swizzle for float2 indices: pad 1 float2 per 16.
#define SW(p) ((p) + ((p) >> 4))

// One workgroup = one row of length 4096.
// IDCT (IDXST=false) or IDXST (IDXST=true) via Makhoul half-spectrum +
// 2048-pt complex unnormalized IFFT (Stockham radix-4 x5 + radix-2 x1) in LDS.
// All twiddles come from the expk table (expk[k] = (cos,sin)(pi*k/8192)):
//   radix-4 stage s twiddle: expk[jm << (12-2s)]            (angle pi/2 * jm/Ns)
//   radix-2 twiddle:         square of expk[4j]             (angle pi*j/1024)
//   Z-build twiddle:         square of expk[2k]             (angle pi*k/2048)
template<bool IDXST>
__global__ __launch_bounds__(256)
void row_fft_kernel(const float* __restrict__ in, float* __restrict__ out,
                    const float2* __restrict__ expk)
{
    __shared__ float smem[8704];              // 34816 B
    float*  xs = smem;                        // [0,4096) staging (real row)
    float2* zb = (float2*)smem;               // 2176 f2, overlays xs (xs dead by then)
    float2* za = (float2*)(smem + 4352);      // 2176 f2

    const int t = threadIdx.x;
    const size_t row = blockIdx.x;
    const float* src = in  + row * 4096;
    float*       dst = out + row * 4096;

    // ---- load row, coalesced float4 ----
    {
        const float4* s4 = (const float4*)src;
        float4* x4 = (float4*)xs;
        #pragma unroll
        for (int i = 0; i < 4; i++) x4[t + 256 * i] = s4[t + 256 * i];
    }
    __syncthreads();

    // ---- build Z_k = A_k + i*B_k (k = 0..2047) ----
    // V_k = 0.5*(X_k - i*Xr_k)*e_k,  e_k = expk[k]
    // A_k = V_k + V_{k+2048};  B_k = (V_k - V_{k+2048}) * exp(i*pi*k/2048)
    // For IDXST the input is X'_k = X_{(4096-k)%4096}, X'_0 = 0.
    #pragma unroll
    for (int i = 0; i < 8; i++) {
        int k = t + 256 * i;                  // 0..2047
        float Xa, Xra, Xb, Xrb;
        if (IDXST) {
            Xa  = (k == 0) ? 0.0f : xs[4096 - k];
            Xra = (k == 0) ? 0.0f : xs[k];
            Xb  = xs[2048 - k];
            Xrb = xs[k + 2048];
        } else {
            Xa  = xs[k];
            Xra = (k == 0) ? 0.0f : xs[4096 - k];
            Xb  = xs[k + 2048];
            Xrb = xs[2048 - k];
        }
        float2 ea = expk[k];
        float2 eb = expk[k + 2048];
        float Var = 0.5f * (Xa * ea.x + Xra * ea.y);
        float Vai = 0.5f * (Xa * ea.y - Xra * ea.x);
        float Vbr = 0.5f * (Xb * eb.x + Xrb * eb.y);
        float Vbi = 0.5f * (Xb * eb.y - Xrb * eb.x);
        float Ar = Var + Vbr, Ai = Vai + Vbi;
        float Dr = Var - Vbr, Di = Vai - Vbi;
        float2 eh = expk[2 * k];              // angle pi*k/4096; square -> pi*k/2048
        float cw = eh.x * eh.x - eh.y * eh.y;
        float sw = 2.0f * eh.x * eh.y;
        float Br = Dr * cw - Di * sw;
        float Bi = Dr * sw + Di * cw;
        za[SW(k)] = make_float2(Ar - Bi, Ai + Br);   // A + i*B
    }
    __syncthreads();

    // ---- 2048-pt complex IFFT (sign = +1, unnormalized), Stockham ----
    float2* sb = za;
    float2* db = zb;
    #pragma unroll
    for (int s = 0; s < 5; s++) {             // radix-4 stages, Ns = 1,4,16,64,256
        const int ls = 2 * s;
        const int Ns = 1 << ls;
        const int shift = 12 - 2 * s;
        #pragma unroll
        for (int ii = 0; ii < 2; ii++) {
            int j = t + 256 * ii;             // 0..511
            float2 v0 = sb[SW(j)];
            float2 v1 = sb[SW(j + 512)];
            float2 v2 = sb[SW(j + 1024)];
            float2 v3 = sb[SW(j + 1536)];
            int jm = j & (Ns - 1);
            float c1, s1;
            if (s == 0) { c1 = 1.0f; s1 = 0.0f; }
            else { float2 e = expk[jm << shift]; c1 = e.x; s1 = e.y; }
            float c2 = c1 * c1 - s1 * s1, s2 = 2.0f * c1 * s1;
            float c3 = c1 * c2 - s1 * s2, s3 = c1 * s2 + s1 * c2;
            if (s != 0) {
                v1 = cmulf(v1, c1, s1);
                v2 = cmulf(v2, c2, s2);
                v3 = cmulf(v3, c3, s3);
            }
            float2 a0 = make_float2(v0.x + v2.x, v0.y + v2.y);
            float2 a1 = make_float2(v0.x - v2.x, v0.y - v2.y);
            float2 a2 = make_float2(v1.x + v3.x, v1.y + v3.y);
            float2 a3 = make_float2(v1.x - v3.x, v1.y - v3.y);
            int idxD = ((j >> ls) << (ls + 2)) | jm;
            db[SW(idxD)]          = make_float2(a0.x + a2.x, a0.y + a2.y);
            db[SW(idxD + Ns)]     = make_float2(a1.x - a3.y, a1.y + a3.x);  // a1 + i*a3
            db[SW(idxD + 2 * Ns)] = make_float2(a0.x - a2.x, a0.y - a2.y);
            db[SW(idxD + 3 * Ns)] = make_float2(a1.x + a3.y, a1.y - a3.x); // a1 - i*a3
        }
        __syncthreads();
        float2* tmp = sb; sb = db; db = tmp;
    }
    // final radix-2 stage: Ns = 1024
    #pragma unroll
    for (int ii = 0; ii < 4; ii++) {
        int j = t + 256 * ii;                 // 0..1023
        float2 v0 = sb[SW(j)];
        float2 v1 = sb[SW(j + 1024)];
        float2 e = expk[4 * j];               // angle pi*j/2048; square -> pi*j/1024
        float c1 = e.x * e.x - e.y * e.y;
        float s1 = 2.0f * e.x * e.y;
        v1 = cmulf(v1, c1, s1);
        db[SW(j)]        = make_float2(v0.x + v1.x, v0.y + v1.y);
        db[SW(j + 1024)] = make_float2(v0.x - v1.x, v0.y - v1.y);
    }
    __syncthreads();
    const float2* zf = db;

    // ---- de-interleave + store (float4 coalesced) ----
    // y_{4p} = Re z_p ; y_{4p+1} = Im z_{2047-p} ; y_{4p+2} = Im z_p ; y_{4p+3} = Re z_{2047-p}
    float4* d4 = (float4*)dst;
    #pragma unroll
    for (int i = 0; i < 4; i++) {
        int p = t + 256 * i;                  // 0..1023
        float2 zp = zf[SW(p)];
        float2 zq = zf[SW(2047 - p)];
        float4 o;
        if (IDXST) {
            o.x = zp.x; o.y = -zq.y; o.z = zp.y; o.w = -zq.x;
        } else {
            o.x = zp.x; o.y =  zq.y; o.z = zp.y; o.w =  zq.x;
        }
        d4[p] = o;
    }
}

// In-place per-batch square transpose (n x n, n % 64 == 0), 64x64 tile pairs.
// Flat 256-thread block (t = threadIdx.x).  float4 global access on both
// sides; scalar LDS with +65 padding (2-way max on the float4 decomposition,
// which is free on gfx950 per m136).
__global__ __launch_bounds__(256)
void transpose_inplace(float* d, int n)
{
    __shared__ float ta[64][65];
    __shared__ float tb[64][65];
    int ti = blockIdx.x, tj = blockIdx.y, b = blockIdx.z;
    if (tj < ti) return;
    float* base = d + (size_t)b * n * n;
    const int t  = threadIdx.x;               // 0..255 (flat block!)
    const int c4 = t & 15;                    // float4 column within tile
    const int r0 = t >> 4;                    // 0..15
    const int n4 = n >> 2;

    float4* A = (float4*)(base + (size_t)(ti * 64) * n + tj * 64);
    float4* B = (float4*)(base + (size_t)(tj * 64) * n + ti * 64);

    #pragma unroll
    for (int i = 0; i < 4; i++) {
        int r = r0 + 16 * i;
        float4 v = A[(size_t)r * n4 + c4];
        ta[r][4 * c4 + 0] = v.x; ta[r][4 * c4 + 1] = v.y;
        ta[r][4 * c4 + 2] = v.z; ta[r][4 * c4 + 3] = v.w;
    }
    if (ti != tj) {
        #pragma unroll
        for (int i = 0; i < 4; i++) {
            int r = r0 + 16 * i;
            float4 v = B[(size_t)r * n4 + c4];
            tb[r][4 * c4 + 0] = v.x; tb[r][4 * c4 + 1] = v.y;
            tb[r][4 * c4 + 2] = v.z; tb[r][4 * c4 + 3] = v.w;
        }
    }
    __syncthreads();
    if (ti != tj) {
        #pragma unroll
        for (int i = 0; i < 4; i++) {
            int r = r0 + 16 * i;
            float4 o, p;
            o.x = tb[4 * c4 + 0][r]; o.y = tb[4 * c4 + 1][r];
            o.z = tb[4 * c4 + 2][r]; o.w = tb[4 * c4 + 3][r];
            A[(size_t)r * n4 + c4] = o;
            p.x = ta[4 * c4 + 0][r]; p.y = ta[4 * c4 + 1][r];
            p.z = ta[4 * c4 + 2][r]; p.w = ta[4 * c4 + 3][r];
            B[(size_t)r * n4 + c4] = p;
        }
    } else {
        #pragma unroll
        for (int i = 0; i < 4; i++) {
            int r = r0 + 16 * i;
            float4 o;
            o.x = ta[4 * c4 + 0][r]; o.y = ta[4 * c4 + 1][r];
            o.z = ta[4 * c4 + 2][r]; o.w = ta[4 * c4 + 3][r];
            A[(size_t)r * n4 + c4] = o;
        }
    }
}

extern "C" void kernel_launch(void* const* d_in, const int* in_sizes, int n_in,
                              void* d_out, int out_size, void* d_ws, size_t ws_size,
                              hipStream_t stream)
{
    const float*  x     = (const float*)d_in[0];
    const float2* expkM = (const float2*)d_in[1];   // (4096, 2) fp32
    const float2* expkN = (const float2*)d_in[2];   // (4096, 2) fp32
    float* out = (float*)d_out;

    const int B = in_sizes[0] / (4096 * 4096);      // = 2
    const int rows = B * 4096;

    // IDXST along N (contiguous rows of x) -> out.  (Transforms on M and N commute.)
    row_fft_kernel<true><<<rows, 256, 0, stream>>>(x, out, expkN);
    // out: (B, M, N) -> (B, N, M)
    transpose_inplace<<<dim3(64, 64, B), dim3(256), 0, stream>>>(out, 4096);
    // IDCT along M (now-contiguous rows), in place.
    row_fft_kernel<false><<<rows, 256, 0, stream>>>(out, out, expkM);
    // back to (B, M, N)
    transpose_inplace<<<dim3(64, 64, B), dim3(256), 0, stream>>>(out, 4096);
}